// Round 12
// baseline (221.231 us; speedup 1.0000x reference)
//
#include <hip/hip_runtime.h>
#include <hip/hip_bf16.h>

#define BB 2
#define TT 1024
#define DD 512
#define HH 8
#define FF 16
#define HDIM 64
#define BT (BB*TT)   // 2048

typedef short bf16x8 __attribute__((ext_vector_type(8)));
typedef float f32x4  __attribute__((ext_vector_type(4)));
#define MFMA_BF16 __builtin_amdgcn_mfma_f32_16x16x32_bf16

// float -> bf16 round-to-nearest-even (scalar)
__device__ __forceinline__ ushort f2b(float f) {
    uint u = __float_as_uint(f);
    uint r = (u + 0x7fffu + ((u >> 16) & 1u)) >> 16;
    return (ushort)r;
}

// pack two floats -> one dword of 2 bf16
__device__ __forceinline__ uint pkbf2(float a, float b) {
    __hip_bfloat162 h = __float22bfloat162_rn(make_float2(a, b));
    union { __hip_bfloat162 h2; uint u; } c; c.h2 = h;
    return c.u;
}

// ---------------------------------------------------------------------------
// Kernel 0: cast inputs to bf16 (round-9 structure, rep-wrapped diagnostic).
// ---------------------------------------------------------------------------
__global__ __launch_bounds__(256) void cast_all(
    const float* __restrict__ X,  const float* __restrict__ Wq,
    const float* __restrict__ Wk, const float* __restrict__ Wv,
    const float* __restrict__ Wo,
    ushort* __restrict__ Xb, ushort* __restrict__ Wb, ushort* __restrict__ Wob,
    int rep)
{
    const int i4 = (blockIdx.x * 256 + threadIdx.x) * 4;
    const float* src; ushort* dst;
    if (i4 < 1048576)      { src = X  + i4;             dst = Xb + i4; }
    else if (i4 < 1114112) { src = Wq + (i4 - 1048576); dst = Wb + (i4 - 1048576); }
    else if (i4 < 1179648) { src = Wk + (i4 - 1114112); dst = Wb + 65536 + (i4 - 1114112); }
    else if (i4 < 1441792) { src = Wv + (i4 - 1179648); dst = Wb + 131072 + (i4 - 1179648); }
    else                   { src = Wo + (i4 - 1441792); dst = Wob + (i4 - 1441792); }
    for (int it = 0; it < rep; ++it) {
        float4 v = *(const float4*)src;
        ushort4 o = { f2b(v.x), f2b(v.y), f2b(v.z), f2b(v.w) };
        *(ushort4*)dst = o;
        asm volatile("" ::: "memory");
    }
}

// ---------------------------------------------------------------------------
// Kernel 1: QKV projection, bf16 MFMA, K-split 8-wave (round-9 structure).
// rep-wrapped diagnostic.
// ---------------------------------------------------------------------------
__global__ __launch_bounds__(512) void qkv_mfma(
    const ushort* __restrict__ Xb, const ushort* __restrict__ Wb,
    ushort* __restrict__ Qb, ushort* __restrict__ Kb, ushort* __restrict__ Vtg,
    int rep)
{
    __shared__ float sc[2][64][66];
    const int m0 = blockIdx.x * 64, n0 = blockIdx.y * 64;
    const int tid = threadIdx.x, w = tid >> 6, l = tid & 63;
    const int kw = w >> 2, mw = w & 1, nw = (w >> 1) & 1;
    const int lr = l & 15, g = l >> 4;

    const ushort* Ar = Xb + (size_t)(m0 + mw*32 + lr) * 512 + kw*256 + g*8;
    const ushort* Br = Wb + (size_t)(n0 + nw*32 + lr) * 512 + kw*256 + g*8;

    for (int it = 0; it < rep; ++it) {
        __syncthreads();   // guard LDS reuse across reps

        f32x4 acc[2][2] = {};
        bf16x8 a0c = *(const bf16x8*)(Ar);
        bf16x8 a1c = *(const bf16x8*)(Ar + (size_t)16*512);
        bf16x8 b0c = *(const bf16x8*)(Br);
        bf16x8 b1c = *(const bf16x8*)(Br + (size_t)16*512);
        #pragma unroll
        for (int ks = 0; ks < 8; ++ks) {
            bf16x8 a0n = a0c, a1n = a1c, b0n = b0c, b1n = b1c;
            if (ks < 7) {
                a0n = *(const bf16x8*)(Ar + (ks+1)*32);
                a1n = *(const bf16x8*)(Ar + (size_t)16*512 + (ks+1)*32);
                b0n = *(const bf16x8*)(Br + (ks+1)*32);
                b1n = *(const bf16x8*)(Br + (size_t)16*512 + (ks+1)*32);
            }
            acc[0][0] = MFMA_BF16(a0c, b0c, acc[0][0], 0, 0, 0);
            acc[0][1] = MFMA_BF16(a0c, b1c, acc[0][1], 0, 0, 0);
            acc[1][0] = MFMA_BF16(a1c, b0c, acc[1][0], 0, 0, 0);
            acc[1][1] = MFMA_BF16(a1c, b1c, acc[1][1], 0, 0, 0);
            a0c = a0n; a1c = a1n; b0c = b0n; b1c = b1n;
        }

        #pragma unroll
        for (int mb = 0; mb < 2; ++mb)
            #pragma unroll
            for (int nb = 0; nb < 2; ++nb)
                #pragma unroll
                for (int r = 0; r < 4; ++r)
                    sc[kw][mw*32 + mb*16 + g*4 + r][nw*32 + nb*16 + lr] = acc[mb][nb][r];
        __syncthreads();

        const int vl = tid & 63, rg = tid >> 6;
        const int cg = n0 + vl;
        float v8[8];
        #pragma unroll
        for (int j = 0; j < 8; ++j) v8[j] = sc[0][rg*8 + j][vl] + sc[1][rg*8 + j][vl];
        const int tok0 = m0 + rg*8;
        const int b = tok0 >> 10, tt0 = tok0 & 1023;
        if (cg < 256) {
            const bool isQ = cg < 128;
            const int c = isQ ? cg : cg - 128;
            const int h = c >> 4, f = c & 15;
            ushort* Dst = isQ ? Qb : Kb;
            #pragma unroll
            for (int j = 0; j < 8; ++j)
                Dst[((size_t)(b*HH + h)*TT + tt0 + j)*FF + f] = f2b(v8[j]);
        } else {
            const int c = cg - 256;
            const int h = c >> 6, v = c & 63;
            uint2 p0 = { pkbf2(v8[0], v8[1]), pkbf2(v8[2], v8[3]) };
            uint2 p1 = { pkbf2(v8[4], v8[5]), pkbf2(v8[6], v8[7]) };
            ushort* base = Vtg + ((size_t)(b*HH + h)*64 + v)*TT + tt0;
            *(uint2*)base       = p0;
            *(uint2*)(base + 4) = p1;
        }
        asm volatile("" ::: "memory");
    }
}

// ---------------------------------------------------------------------------
// Kernel 2: causal Taylor attention, bf16 MFMA, 8-wave split-K (round-9
// structure), rep-wrapped diagnostic.
// ---------------------------------------------------------------------------
__global__ __launch_bounds__(512) void attn_mfma(
    const ushort* __restrict__ Qb, const ushort* __restrict__ Kb,
    const ushort* __restrict__ Vtg, ushort* __restrict__ Yb, int rep)
{
    __shared__ float smem[8*32*68 + 8*32];           // 70656 B
    short (*Pl)[32][72] = (short(*)[32][72])smem;    // [wave][q32][k64+8]
    float* scf = smem;                               // epi: [8][32][68]
    float* scd = smem + 8*32*68;                     // epi: [8][32]

    const int bid = blockIdx.x;
    const int qt = 31 - (bid >> 4);       // heavy q-tiles dispatch first (LPT)
    const int bh = bid & 15;
    const int b = bh >> 3, h = bh & 7;
    const int tid = threadIdx.x, w = tid >> 6, l = tid & 63;
    const int lr = l & 15, g = l >> 4;
    const int nkc = (qt + 2) >> 1;
    const bf16x8 zf = {0,0,0,0,0,0,0,0};

    bf16x8 qf[2];
    #pragma unroll
    for (int nb = 0; nb < 2; ++nb)
        qf[nb] = (l < 32)
            ? *(const bf16x8*)(Qb + ((size_t)bh*TT + qt*32 + nb*16 + lr)*FF + g*8)
            : zf;

    for (int it = 0; it < rep; ++it) {
        __syncthreads();   // guard LDS overlay across reps

        f32x4 o[4][2] = {};
        float den[2] = {0.f, 0.f};

        for (int kc = w; kc < nkc; kc += 8) {
            #pragma unroll
            for (int mb = 0; mb < 4; ++mb) {
                bf16x8 kf = (l < 32)
                    ? *(const bf16x8*)(Kb + ((size_t)bh*TT + kc*64 + mb*16 + lr)*FF + g*8)
                    : zf;
                #pragma unroll
                for (int nb = 0; nb < 2; ++nb) {
                    f32x4 z4 = {};
                    f32x4 s = MFMA_BF16(kf, qf[nb], z4, 0, 0, 0);
                    const int qg = qt*32 + nb*16 + lr;
                    const int kg0 = kc*64 + mb*16 + g*4;
                    float pv[4];
                    #pragma unroll
                    for (int r = 0; r < 4; ++r) {
                        float ss = s[r] * 0.25f;
                        float pp = fmaf(ss, fmaf(ss, 0.5f, 1.0f), 1.0f);
                        if (kg0 + r > qg) pp = 0.f;
                        den[nb] += pp;
                        pv[r] = pp;
                    }
                    uint2 pk = { pkbf2(pv[0], pv[1]), pkbf2(pv[2], pv[3]) };
                    *(uint2*)&Pl[w][nb*16 + lr][mb*16 + g*4] = pk;
                }
            }

            #pragma unroll
            for (int kb = 0; kb < 2; ++kb)
                #pragma unroll
                for (int mv = 0; mv < 4; ++mv) {
                    bf16x8 vf = *(const bf16x8*)(Vtg +
                        ((size_t)bh*64 + mv*16 + lr)*TT + kc*64 + kb*32 + g*8);
                    #pragma unroll
                    for (int nb = 0; nb < 2; ++nb) {
                        bf16x8 pf = *(const bf16x8*)&Pl[w][nb*16 + lr][kb*32 + g*8];
                        o[mv][nb] = MFMA_BF16(vf, pf, o[mv][nb], 0, 0, 0);
                    }
                }
        }

        float dred[2];
        #pragma unroll
        for (int nb = 0; nb < 2; ++nb) {
            float d = den[nb];
            d += __shfl_xor(d, 16);
            d += __shfl_xor(d, 32);
            dred[nb] = d;
        }

        __syncthreads();

        #pragma unroll
        for (int mv = 0; mv < 4; ++mv)
            #pragma unroll
            for (int nb = 0; nb < 2; ++nb)
                *(f32x4*)&scf[(size_t)(w*32 + nb*16 + lr)*68 + mv*16 + g*4] = o[mv][nb];
        if (g == 0) {
            scd[w*32 + lr]      = dred[0];
            scd[w*32 + 16 + lr] = dred[1];
        }

        __syncthreads();

        {
            const int q  = tid >> 4;
            const int v0 = (tid & 15) * 4;
            float dtot = 0.f;
            #pragma unroll
            for (int ww = 0; ww < 8; ++ww) dtot += scd[ww*32 + q];
            const float inv = 1.0f / (dtot + 1e-12f);
            float o0 = 0.f, o1 = 0.f, o2 = 0.f, o3 = 0.f;
            #pragma unroll
            for (int ww = 0; ww < 8; ++ww) {
                const float* p = &scf[(size_t)(ww*32 + q)*68 + v0];
                o0 += p[0]; o1 += p[1]; o2 += p[2]; o3 += p[3];
            }
            uint2 pk = { pkbf2(o0*inv, o1*inv), pkbf2(o2*inv, o3*inv) };
            *(uint2*)(Yb + ((size_t)(b*TT + qt*32 + q))*DD + h*HDIM + v0) = pk;
        }
        asm volatile("" ::: "memory");
    }
}

// ---------------------------------------------------------------------------
// Kernel 3: output projection, bf16 MFMA, K-split 8-wave (round-9 structure),
// rep-wrapped diagnostic.
// ---------------------------------------------------------------------------
__global__ __launch_bounds__(512) void out_mfma(
    const ushort* __restrict__ Yb, const ushort* __restrict__ Wob,
    float* __restrict__ Out, int rep)
{
    __shared__ float sc[2][64][66];
    const int m0 = blockIdx.x * 64, n0 = blockIdx.y * 64;
    const int tid = threadIdx.x, w = tid >> 6, l = tid & 63;
    const int kw = w >> 2, mw = w & 1, nw = (w >> 1) & 1;
    const int lr = l & 15, g = l >> 4;

    const ushort* Ar = Yb  + (size_t)(m0 + mw*32 + lr) * 512 + kw*256 + g*8;
    const ushort* Br = Wob + (size_t)(n0 + nw*32 + lr) * 512 + kw*256 + g*8;

    for (int it = 0; it < rep; ++it) {
        __syncthreads();   // guard LDS reuse across reps

        f32x4 acc[2][2] = {};
        bf16x8 a0c = *(const bf16x8*)(Ar);
        bf16x8 a1c = *(const bf16x8*)(Ar + (size_t)16*512);
        bf16x8 b0c = *(const bf16x8*)(Br);
        bf16x8 b1c = *(const bf16x8*)(Br + (size_t)16*512);
        #pragma unroll
        for (int ks = 0; ks < 8; ++ks) {
            bf16x8 a0n = a0c, a1n = a1c, b0n = b0c, b1n = b1c;
            if (ks < 7) {
                a0n = *(const bf16x8*)(Ar + (ks+1)*32);
                a1n = *(const bf16x8*)(Ar + (size_t)16*512 + (ks+1)*32);
                b0n = *(const bf16x8*)(Br + (ks+1)*32);
                b1n = *(const bf16x8*)(Br + (size_t)16*512 + (ks+1)*32);
            }
            acc[0][0] = MFMA_BF16(a0c, b0c, acc[0][0], 0, 0, 0);
            acc[0][1] = MFMA_BF16(a0c, b1c, acc[0][1], 0, 0, 0);
            acc[1][0] = MFMA_BF16(a1c, b0c, acc[1][0], 0, 0, 0);
            acc[1][1] = MFMA_BF16(a1c, b1c, acc[1][1], 0, 0, 0);
            a0c = a0n; a1c = a1n; b0c = b0n; b1c = b1n;
        }

        #pragma unroll
        for (int mb = 0; mb < 2; ++mb)
            #pragma unroll
            for (int nb = 0; nb < 2; ++nb)
                #pragma unroll
                for (int r = 0; r < 4; ++r)
                    sc[kw][mw*32 + mb*16 + g*4 + r][nw*32 + nb*16 + lr] = acc[mb][nb][r];
        __syncthreads();

        const int vl = tid & 63, rg = tid >> 6;
        #pragma unroll
        for (int j = 0; j < 8; ++j) {
            const float v = sc[0][rg*8 + j][vl] + sc[1][rg*8 + j][vl];
            Out[(size_t)(m0 + rg*8 + j)*512 + n0 + vl] = v;
        }
        asm volatile("" ::: "memory");
    }
}

// ---------------------------------------------------------------------------
extern "C" void kernel_launch(void* const* d_in, const int* in_sizes, int n_in,
                              void* d_out, int out_size, void* d_ws, size_t ws_size,
                              hipStream_t stream) {
    const float* X  = (const float*)d_in[0];   // (2,1024,512)
    const float* Wq = (const float*)d_in[1];   // (128,512)
    const float* Wk = (const float*)d_in[2];   // (128,512)
    const float* Wv = (const float*)d_in[3];   // (512,512)
    const float* Wo = (const float*)d_in[4];   // (512,512)
    float* out = (float*)d_out;                // (2,1024,512)

    ushort* ws = (ushort*)d_ws;
    ushort* Xb  = ws;                    // 2048*512   = 1048576
    ushort* Wb  = Xb  + 1048576;         // 768*512    = 393216
    ushort* Wob = Wb  + 393216;          // 512*512    = 262144
    ushort* Qb  = Wob + 262144;          // 16*1024*16 = 262144
    ushort* Kb  = Qb  + 262144;          // 262144
    ushort* Vtg = Kb  + 262144;          // 16*64*1024 = 1048576
    ushort* Yb  = Vtg + 1048576;         // 2048*512   = 1048576

    // DIAGNOSTIC ROUND 2: rep factors push all four round-9 kernels above the
    // ~40us poison-fill floor so each gets a full counter row in the top-5.
    const int REP_CAST = 12, REP_QKV = 8, REP_ATTN = 20, REP_OUT = 8;

    cast_all<<<1664, 256, 0, stream>>>(X, Wq, Wk, Wv, Wo, Xb, Wb, Wob, REP_CAST);

    dim3 g1(BT/64, 768/64);   // 32 x 12 = 384 blocks, 512 thr
    qkv_mfma<<<g1, 512, 0, stream>>>(Xb, Wb, Qb, Kb, Vtg, REP_QKV);

    attn_mfma<<<512, 512, 0, stream>>>(Qb, Kb, Vtg, Yb, REP_ATTN);

    dim3 g3(BT/64, DD/64);    // 32 x 8 = 256 blocks, 512 thr
    out_mfma<<<g3, 512, 0, stream>>>(Yb, Wob, out, REP_OUT);
}

// Round 13
// 50.125 us; speedup vs baseline: 4.4136x; 4.4136x over previous
//
#include <hip/hip_runtime.h>
#include <hip/hip_bf16.h>

#define BB 2
#define TT 1024
#define DD 512
#define HH 8
#define FF 16
#define HDIM 64
#define BT (BB*TT)   // 2048

typedef short bf16x8 __attribute__((ext_vector_type(8)));
typedef float f32x4  __attribute__((ext_vector_type(4)));
#define MFMA_BF16 __builtin_amdgcn_mfma_f32_16x16x32_bf16

// float -> bf16 round-to-nearest-even (scalar)
__device__ __forceinline__ ushort f2b(float f) {
    uint u = __float_as_uint(f);
    uint r = (u + 0x7fffu + ((u >> 16) & 1u)) >> 16;
    return (ushort)r;
}

// pack two floats -> one dword of 2 bf16
__device__ __forceinline__ uint pkbf2(float a, float b) {
    __hip_bfloat162 h = __float22bfloat162_rn(make_float2(a, b));
    union { __hip_bfloat162 h2; uint u; } c; c.h2 = h;
    return c.u;
}

// ---------------------------------------------------------------------------
// Kernel 0: cast inputs to bf16 (round-9 structure, unchanged).
// ---------------------------------------------------------------------------
__global__ __launch_bounds__(256) void cast_all(
    const float* __restrict__ X,  const float* __restrict__ Wq,
    const float* __restrict__ Wk, const float* __restrict__ Wv,
    const float* __restrict__ Wo,
    ushort* __restrict__ Xb, ushort* __restrict__ Wb, ushort* __restrict__ Wob)
{
    const int i4 = (blockIdx.x * 256 + threadIdx.x) * 4;
    const float* src; ushort* dst;
    if (i4 < 1048576)      { src = X  + i4;             dst = Xb + i4; }
    else if (i4 < 1114112) { src = Wq + (i4 - 1048576); dst = Wb + (i4 - 1048576); }
    else if (i4 < 1179648) { src = Wk + (i4 - 1114112); dst = Wb + 65536 + (i4 - 1114112); }
    else if (i4 < 1441792) { src = Wv + (i4 - 1179648); dst = Wb + 131072 + (i4 - 1179648); }
    else                   { src = Wo + (i4 - 1441792); dst = Wob + (i4 - 1441792); }
    float4 v = *(const float4*)src;
    ushort4 o = { f2b(v.x), f2b(v.y), f2b(v.z), f2b(v.w) };
    *(ushort4*)dst = o;
}

// ---------------------------------------------------------------------------
// Kernel 1: QKV projection, bf16 MFMA, K-split 8-wave (round-9 structure).
// ONE change: K output pre-scaled by 0.25 (exact pow2; moves attention's
// s = (q.k)/4 scaling into the K store for free).
// ---------------------------------------------------------------------------
__global__ __launch_bounds__(512) void qkv_mfma(
    const ushort* __restrict__ Xb, const ushort* __restrict__ Wb,
    ushort* __restrict__ Qb, ushort* __restrict__ Kb, ushort* __restrict__ Vtg)
{
    __shared__ float sc[2][64][66];
    const int m0 = blockIdx.x * 64, n0 = blockIdx.y * 64;
    const int tid = threadIdx.x, w = tid >> 6, l = tid & 63;
    const int kw = w >> 2, mw = w & 1, nw = (w >> 1) & 1;
    const int lr = l & 15, g = l >> 4;

    f32x4 acc[2][2] = {};
    const ushort* Ar = Xb + (size_t)(m0 + mw*32 + lr) * 512 + kw*256 + g*8;
    const ushort* Br = Wb + (size_t)(n0 + nw*32 + lr) * 512 + kw*256 + g*8;

    bf16x8 a0c = *(const bf16x8*)(Ar);
    bf16x8 a1c = *(const bf16x8*)(Ar + (size_t)16*512);
    bf16x8 b0c = *(const bf16x8*)(Br);
    bf16x8 b1c = *(const bf16x8*)(Br + (size_t)16*512);
    #pragma unroll
    for (int ks = 0; ks < 8; ++ks) {
        bf16x8 a0n = a0c, a1n = a1c, b0n = b0c, b1n = b1c;
        if (ks < 7) {
            a0n = *(const bf16x8*)(Ar + (ks+1)*32);
            a1n = *(const bf16x8*)(Ar + (size_t)16*512 + (ks+1)*32);
            b0n = *(const bf16x8*)(Br + (ks+1)*32);
            b1n = *(const bf16x8*)(Br + (size_t)16*512 + (ks+1)*32);
        }
        acc[0][0] = MFMA_BF16(a0c, b0c, acc[0][0], 0, 0, 0);
        acc[0][1] = MFMA_BF16(a0c, b1c, acc[0][1], 0, 0, 0);
        acc[1][0] = MFMA_BF16(a1c, b0c, acc[1][0], 0, 0, 0);
        acc[1][1] = MFMA_BF16(a1c, b1c, acc[1][1], 0, 0, 0);
        a0c = a0n; a1c = a1n; b0c = b0n; b1c = b1n;
    }

    #pragma unroll
    for (int mb = 0; mb < 2; ++mb)
        #pragma unroll
        for (int nb = 0; nb < 2; ++nb)
            #pragma unroll
            for (int r = 0; r < 4; ++r)
                sc[kw][mw*32 + mb*16 + g*4 + r][nw*32 + nb*16 + lr] = acc[mb][nb][r];
    __syncthreads();

    const int vl = tid & 63, rg = tid >> 6;
    const int cg = n0 + vl;
    float v8[8];
    #pragma unroll
    for (int j = 0; j < 8; ++j) v8[j] = sc[0][rg*8 + j][vl] + sc[1][rg*8 + j][vl];
    const int tok0 = m0 + rg*8;
    const int b = tok0 >> 10, tt0 = tok0 & 1023;
    if (cg < 256) {
        const bool isQ = cg < 128;
        const int c = isQ ? cg : cg - 128;
        const int h = c >> 4, f = c & 15;
        ushort* Dst = isQ ? Qb : Kb;
        const float scale = isQ ? 1.0f : 0.25f;   // pre-scale K by 1/4
        #pragma unroll
        for (int j = 0; j < 8; ++j)
            Dst[((size_t)(b*HH + h)*TT + tt0 + j)*FF + f] = f2b(v8[j] * scale);
    } else {
        const int c = cg - 256;
        const int h = c >> 6, v = c & 63;
        uint2 p0 = { pkbf2(v8[0], v8[1]), pkbf2(v8[2], v8[3]) };
        uint2 p1 = { pkbf2(v8[4], v8[5]), pkbf2(v8[6], v8[7]) };
        ushort* base = Vtg + ((size_t)(b*HH + h)*64 + v)*TT + tt0;
        *(uint2*)base       = p0;
        *(uint2*)(base + 4) = p1;
    }
}

// ---------------------------------------------------------------------------
// Kernel 2: causal Taylor attention, bf16 MFMA, 8-wave split-K, OCCUPANCY
// REBUILD.  phi(q).phi(k) = 1 + s + s^2/2, s = q.k_scaled (K pre-scaled 1/4).
// Grid: 1024 blocks = (qt 0..63 desc [LPT], bh), 512 threads (8 waves).
// Block = 16 q-rows; wave w: key-chunks kc = w, w+8, ... (64 keys each).
// LDS 18.4KB (vs 70.7KB) -> 4 blocks/CU = 32 waves/CU.
// VALU diet: poly = 2 fma (K pre-scaled); causal cndmask only on the
// wave-uniform diagonal chunk; den via ones-fragment MFMA inside PV
// (all lanes end up holding den[q] -- no shuffle reduce).
// Epilogue: 2-stage wave-partial combine through [4]-slot f32 LDS scratch.
// ---------------------------------------------------------------------------
__global__ __launch_bounds__(512) void attn_mfma(
    const ushort* __restrict__ Qb, const ushort* __restrict__ Kb,
    const ushort* __restrict__ Vtg, ushort* __restrict__ Yb)
{
    __shared__ float smem[4608];                      // 18432 B
    short (*Pl)[16][72] = (short(*)[16][72])smem;     // [wave][q16][k64+8]
    float* scf = smem;                                // epi: [4][16][68]
    float* scd = smem + 4*16*68;                      // epi: [4][16]

    const int bid = blockIdx.x;
    const int qt = 63 - (bid >> 4);       // heavy q-tiles dispatch first (LPT)
    const int bh = bid & 15;
    const int b = bh >> 3, h = bh & 7;
    const int tid = threadIdx.x, w = tid >> 6, l = tid & 63;
    const int lr = l & 15, g = l >> 4;
    const int qend = (qt + 1) * 16;
    const int nkc = (qend + 63) >> 6;
    const bf16x8 zf = {0,0,0,0,0,0,0,0};
    const bf16x8 ones = {16256,16256,16256,16256,16256,16256,16256,16256}; // bf16 1.0

    // Q B-fragment (f=16: k-groups g>=2 are zero)
    bf16x8 qf = (l < 32)
        ? *(const bf16x8*)(Qb + ((size_t)bh*TT + qt*16 + lr)*FF + g*8)
        : zf;

    f32x4 o[4] = {};      // o[mv][r]: v-dim mv*16+g*4+r, q = lr
    f32x4 dacc = {};      // den[q=lr], replicated across regs/groups

    for (int kc = w; kc < nkc; kc += 8) {
        const bool diagc = (kc == nkc - 1);           // wave-uniform
        const int act = qend - kc*64;                 // active keys (mult of 16)
        const int nmb = diagc ? (act >> 4) : 4;
        const int kb_max = diagc ? ((nmb + 1) >> 1) : 2;

        // QK^T (swapped: mfma(K,Q) -> S^T), poly, pack -> P
        for (int mb = 0; mb < nmb; ++mb) {
            bf16x8 kf = (l < 32)
                ? *(const bf16x8*)(Kb + ((size_t)bh*TT + kc*64 + mb*16 + lr)*FF + g*8)
                : zf;
            f32x4 z4 = {};
            f32x4 s = MFMA_BF16(kf, qf, z4, 0, 0, 0); // s = q.k/4 (pre-scaled)
            float pv[4];
            if (diagc) {
                const int qg = qt*16 + lr;
                const int kg0 = kc*64 + mb*16 + g*4;
                #pragma unroll
                for (int r = 0; r < 4; ++r) {
                    float pp = fmaf(s[r], fmaf(s[r], 0.5f, 1.0f), 1.0f);
                    pv[r] = (kg0 + r > qg) ? 0.f : pp;
                }
            } else {
                #pragma unroll
                for (int r = 0; r < 4; ++r)
                    pv[r] = fmaf(s[r], fmaf(s[r], 0.5f, 1.0f), 1.0f);
            }
            uint2 pk = { pkbf2(pv[0], pv[1]), pkbf2(pv[2], pv[3]) };
            *(uint2*)&Pl[w][lr][mb*16 + g*4] = pk;
        }
        for (int mb = nmb; mb < kb_max*2; ++mb) {     // zero partial P tiles
            uint2 zz = {0u, 0u};
            *(uint2*)&Pl[w][lr][mb*16 + g*4] = zz;
        }

        // PV + den:  O^T += V^T . P ;  den += ones . P
        for (int kb = 0; kb < kb_max; ++kb) {
            bf16x8 pf = *(const bf16x8*)&Pl[w][lr][kb*32 + g*8];
            #pragma unroll
            for (int mv = 0; mv < 4; ++mv) {
                bf16x8 vf = *(const bf16x8*)(Vtg +
                    ((size_t)bh*64 + mv*16 + lr)*TT + kc*64 + kb*32 + g*8);
                o[mv] = MFMA_BF16(vf, pf, o[mv], 0, 0, 0);
            }
            dacc = MFMA_BF16(ones, pf, dacc, 0, 0, 0);
        }
    }

    __syncthreads();   // all waves done reading Pl (scratch overlays it)

    // stage A: waves 4-7 dump partials into slots 0-3
    if (w >= 4) {
        #pragma unroll
        for (int mv = 0; mv < 4; ++mv)
            *(f32x4*)&scf[(size_t)((w-4)*16 + lr)*68 + mv*16 + g*4] = o[mv];
        if (l < 16) scd[(w-4)*16 + lr] = dacc[0];
    }
    __syncthreads();

    // stage B: waves 0-3 add partner partials, write back
    if (w < 4) {
        #pragma unroll
        for (int mv = 0; mv < 4; ++mv) {
            f32x4 p = *(const f32x4*)&scf[(size_t)(w*16 + lr)*68 + mv*16 + g*4];
            o[mv] = o[mv] + p;
            *(f32x4*)&scf[(size_t)(w*16 + lr)*68 + mv*16 + g*4] = o[mv];
        }
        if (l < 16) scd[w*16 + lr] += dacc[0];
    }
    __syncthreads();

    // stage C: combine 4 slots, normalize, store bf16 Y (8B/thread coalesced)
    if (tid < 256) {
        const int q  = tid >> 4;           // 0..15
        const int v0 = (tid & 15) * 4;     // 0..60
        const float dtot = scd[q] + scd[16 + q] + scd[32 + q] + scd[48 + q];
        const float inv = 1.0f / (dtot + 1e-12f);
        float o0 = 0.f, o1 = 0.f, o2 = 0.f, o3 = 0.f;
        #pragma unroll
        for (int s4 = 0; s4 < 4; ++s4) {
            const float* p = &scf[(size_t)(s4*16 + q)*68 + v0];
            o0 += p[0]; o1 += p[1]; o2 += p[2]; o3 += p[3];
        }
        uint2 pk = { pkbf2(o0*inv, o1*inv), pkbf2(o2*inv, o3*inv) };
        *(uint2*)(Yb + ((size_t)(b*TT + qt*16 + q))*DD + h*HDIM + v0) = pk;
    }
}

// ---------------------------------------------------------------------------
// Kernel 3: output projection, bf16 MFMA, K-split 8-wave (round-9 structure,
// unchanged).
// ---------------------------------------------------------------------------
__global__ __launch_bounds__(512) void out_mfma(
    const ushort* __restrict__ Yb, const ushort* __restrict__ Wob,
    float* __restrict__ Out)
{
    __shared__ float sc[2][64][66];
    const int m0 = blockIdx.x * 64, n0 = blockIdx.y * 64;
    const int tid = threadIdx.x, w = tid >> 6, l = tid & 63;
    const int kw = w >> 2, mw = w & 1, nw = (w >> 1) & 1;
    const int lr = l & 15, g = l >> 4;

    f32x4 acc[2][2] = {};
    const ushort* Ar = Yb  + (size_t)(m0 + mw*32 + lr) * 512 + kw*256 + g*8;
    const ushort* Br = Wob + (size_t)(n0 + nw*32 + lr) * 512 + kw*256 + g*8;

    bf16x8 a0c = *(const bf16x8*)(Ar);
    bf16x8 a1c = *(const bf16x8*)(Ar + (size_t)16*512);
    bf16x8 b0c = *(const bf16x8*)(Br);
    bf16x8 b1c = *(const bf16x8*)(Br + (size_t)16*512);
    #pragma unroll
    for (int ks = 0; ks < 8; ++ks) {
        bf16x8 a0n = a0c, a1n = a1c, b0n = b0c, b1n = b1c;
        if (ks < 7) {
            a0n = *(const bf16x8*)(Ar + (ks+1)*32);
            a1n = *(const bf16x8*)(Ar + (size_t)16*512 + (ks+1)*32);
            b0n = *(const bf16x8*)(Br + (ks+1)*32);
            b1n = *(const bf16x8*)(Br + (size_t)16*512 + (ks+1)*32);
        }
        acc[0][0] = MFMA_BF16(a0c, b0c, acc[0][0], 0, 0, 0);
        acc[0][1] = MFMA_BF16(a0c, b1c, acc[0][1], 0, 0, 0);
        acc[1][0] = MFMA_BF16(a1c, b0c, acc[1][0], 0, 0, 0);
        acc[1][1] = MFMA_BF16(a1c, b1c, acc[1][1], 0, 0, 0);
        a0c = a0n; a1c = a1n; b0c = b0n; b1c = b1n;
    }

    #pragma unroll
    for (int mb = 0; mb < 2; ++mb)
        #pragma unroll
        for (int nb = 0; nb < 2; ++nb)
            #pragma unroll
            for (int r = 0; r < 4; ++r)
                sc[kw][mw*32 + mb*16 + g*4 + r][nw*32 + nb*16 + lr] = acc[mb][nb][r];
    __syncthreads();

    const int vl = tid & 63, rg = tid >> 6;
    #pragma unroll
    for (int j = 0; j < 8; ++j) {
        const float v = sc[0][rg*8 + j][vl] + sc[1][rg*8 + j][vl];
        Out[(size_t)(m0 + rg*8 + j)*512 + n0 + vl] = v;
    }
}

// ---------------------------------------------------------------------------
extern "C" void kernel_launch(void* const* d_in, const int* in_sizes, int n_in,
                              void* d_out, int out_size, void* d_ws, size_t ws_size,
                              hipStream_t stream) {
    const float* X  = (const float*)d_in[0];   // (2,1024,512)
    const float* Wq = (const float*)d_in[1];   // (128,512)
    const float* Wk = (const float*)d_in[2];   // (128,512)
    const float* Wv = (const float*)d_in[3];   // (512,512)
    const float* Wo = (const float*)d_in[4];   // (512,512)
    float* out = (float*)d_out;                // (2,1024,512)

    ushort* ws = (ushort*)d_ws;
    ushort* Xb  = ws;                    // 2048*512   = 1048576
    ushort* Wb  = Xb  + 1048576;         // 768*512    = 393216
    ushort* Wob = Wb  + 393216;          // 512*512    = 262144
    ushort* Qb  = Wob + 262144;          // 16*1024*16 = 262144
    ushort* Kb  = Qb  + 262144;          // 262144
    ushort* Vtg = Kb  + 262144;          // 16*64*1024 = 1048576
    ushort* Yb  = Vtg + 1048576;         // 2048*512   = 1048576

    cast_all<<<1664, 256, 0, stream>>>(X, Wq, Wk, Wv, Wo, Xb, Wb, Wob);

    dim3 g1(BT/64, 768/64);   // 32 x 12 = 384 blocks, 512 thr
    qkv_mfma<<<g1, 512, 0, stream>>>(Xb, Wb, Qb, Kb, Vtg);

    attn_mfma<<<1024, 512, 0, stream>>>(Qb, Kb, Vtg, Yb);

    dim3 g3(BT/64, DD/64);    // 32 x 8 = 256 blocks, 512 thr
    out_mfma<<<g3, 512, 0, stream>>>(Yb, Wob, out);
}

// Round 14
// 47.746 us; speedup vs baseline: 4.6335x; 1.0498x over previous
//
#include <hip/hip_runtime.h>
#include <hip/hip_bf16.h>

#define BB 2
#define TT 1024
#define DD 512
#define HH 8
#define FF 16
#define HDIM 64
#define BT (BB*TT)   // 2048

typedef short bf16x8 __attribute__((ext_vector_type(8)));
typedef float f32x4  __attribute__((ext_vector_type(4)));
#define MFMA_BF16 __builtin_amdgcn_mfma_f32_16x16x32_bf16

// float -> bf16 round-to-nearest-even (scalar)
__device__ __forceinline__ ushort f2b(float f) {
    uint u = __float_as_uint(f);
    uint r = (u + 0x7fffu + ((u >> 16) & 1u)) >> 16;
    return (ushort)r;
}

// pack two floats -> one dword of 2 bf16
__device__ __forceinline__ uint pkbf2(float a, float b) {
    __hip_bfloat162 h = __float22bfloat162_rn(make_float2(a, b));
    union { __hip_bfloat162 h2; uint u; } c; c.h2 = h;
    return c.u;
}

// ---------------------------------------------------------------------------
// Kernel 0: cast inputs to bf16 (round-9 structure, unchanged).
// ---------------------------------------------------------------------------
__global__ __launch_bounds__(256) void cast_all(
    const float* __restrict__ X,  const float* __restrict__ Wq,
    const float* __restrict__ Wk, const float* __restrict__ Wv,
    const float* __restrict__ Wo,
    ushort* __restrict__ Xb, ushort* __restrict__ Wb, ushort* __restrict__ Wob)
{
    const int i4 = (blockIdx.x * 256 + threadIdx.x) * 4;
    const float* src; ushort* dst;
    if (i4 < 1048576)      { src = X  + i4;             dst = Xb + i4; }
    else if (i4 < 1114112) { src = Wq + (i4 - 1048576); dst = Wb + (i4 - 1048576); }
    else if (i4 < 1179648) { src = Wk + (i4 - 1114112); dst = Wb + 65536 + (i4 - 1114112); }
    else if (i4 < 1441792) { src = Wv + (i4 - 1179648); dst = Wb + 131072 + (i4 - 1179648); }
    else                   { src = Wo + (i4 - 1441792); dst = Wob + (i4 - 1441792); }
    float4 v = *(const float4*)src;
    ushort4 o = { f2b(v.x), f2b(v.y), f2b(v.z), f2b(v.w) };
    *(ushort4*)dst = o;
}

// ---------------------------------------------------------------------------
// Kernel 1: QKV projection, bf16 MFMA, K-split 8-wave (round-9 structure).
// ONE change vs round 9: K output pre-scaled by 0.25 (exact pow2; moves
// attention's s = (q.k)/4 scaling into the K store).
// ---------------------------------------------------------------------------
__global__ __launch_bounds__(512) void qkv_mfma(
    const ushort* __restrict__ Xb, const ushort* __restrict__ Wb,
    ushort* __restrict__ Qb, ushort* __restrict__ Kb, ushort* __restrict__ Vtg)
{
    __shared__ float sc[2][64][66];
    const int m0 = blockIdx.x * 64, n0 = blockIdx.y * 64;
    const int tid = threadIdx.x, w = tid >> 6, l = tid & 63;
    const int kw = w >> 2, mw = w & 1, nw = (w >> 1) & 1;
    const int lr = l & 15, g = l >> 4;

    f32x4 acc[2][2] = {};
    const ushort* Ar = Xb + (size_t)(m0 + mw*32 + lr) * 512 + kw*256 + g*8;
    const ushort* Br = Wb + (size_t)(n0 + nw*32 + lr) * 512 + kw*256 + g*8;

    bf16x8 a0c = *(const bf16x8*)(Ar);
    bf16x8 a1c = *(const bf16x8*)(Ar + (size_t)16*512);
    bf16x8 b0c = *(const bf16x8*)(Br);
    bf16x8 b1c = *(const bf16x8*)(Br + (size_t)16*512);
    #pragma unroll
    for (int ks = 0; ks < 8; ++ks) {
        bf16x8 a0n = a0c, a1n = a1c, b0n = b0c, b1n = b1c;
        if (ks < 7) {
            a0n = *(const bf16x8*)(Ar + (ks+1)*32);
            a1n = *(const bf16x8*)(Ar + (size_t)16*512 + (ks+1)*32);
            b0n = *(const bf16x8*)(Br + (ks+1)*32);
            b1n = *(const bf16x8*)(Br + (size_t)16*512 + (ks+1)*32);
        }
        acc[0][0] = MFMA_BF16(a0c, b0c, acc[0][0], 0, 0, 0);
        acc[0][1] = MFMA_BF16(a0c, b1c, acc[0][1], 0, 0, 0);
        acc[1][0] = MFMA_BF16(a1c, b0c, acc[1][0], 0, 0, 0);
        acc[1][1] = MFMA_BF16(a1c, b1c, acc[1][1], 0, 0, 0);
        a0c = a0n; a1c = a1n; b0c = b0n; b1c = b1n;
    }

    #pragma unroll
    for (int mb = 0; mb < 2; ++mb)
        #pragma unroll
        for (int nb = 0; nb < 2; ++nb)
            #pragma unroll
            for (int r = 0; r < 4; ++r)
                sc[kw][mw*32 + mb*16 + g*4 + r][nw*32 + nb*16 + lr] = acc[mb][nb][r];
    __syncthreads();

    const int vl = tid & 63, rg = tid >> 6;
    const int cg = n0 + vl;
    float v8[8];
    #pragma unroll
    for (int j = 0; j < 8; ++j) v8[j] = sc[0][rg*8 + j][vl] + sc[1][rg*8 + j][vl];
    const int tok0 = m0 + rg*8;
    const int b = tok0 >> 10, tt0 = tok0 & 1023;
    if (cg < 256) {
        const bool isQ = cg < 128;
        const int c = isQ ? cg : cg - 128;
        const int h = c >> 4, f = c & 15;
        ushort* Dst = isQ ? Qb : Kb;
        const float scale = isQ ? 1.0f : 0.25f;   // pre-scale K by 1/4
        #pragma unroll
        for (int j = 0; j < 8; ++j)
            Dst[((size_t)(b*HH + h)*TT + tt0 + j)*FF + f] = f2b(v8[j] * scale);
    } else {
        const int c = cg - 256;
        const int h = c >> 6, v = c & 63;
        uint2 p0 = { pkbf2(v8[0], v8[1]), pkbf2(v8[2], v8[3]) };
        uint2 p1 = { pkbf2(v8[4], v8[5]), pkbf2(v8[6], v8[7]) };
        ushort* base = Vtg + ((size_t)(b*HH + h)*64 + v)*TT + tt0;
        *(uint2*)base       = p0;
        *(uint2*)(base + 4) = p1;
    }
}

// ---------------------------------------------------------------------------
// Kernel 2: causal Taylor attention, bf16 MFMA, 8-wave split-K — round-9
// structure (32 q-rows/block, 512 blocks, 70.7KB LDS) with VALU diet only:
//  - s arrives pre-scaled (K stored /4): poly = 2 fma
//  - causal mask only on the wave-uniform diagonal chunk
//  - diagonal chunk skips fully-masked 16-key tiles (nmb = 2 or 4, even)
//  - den folded into PV as a ones-fragment MFMA (no shuffle reduce)
// ---------------------------------------------------------------------------
__global__ __launch_bounds__(512) void attn_mfma(
    const ushort* __restrict__ Qb, const ushort* __restrict__ Kb,
    const ushort* __restrict__ Vtg, ushort* __restrict__ Yb)
{
    __shared__ float smem[8*32*68 + 8*32];           // 70656 B
    short (*Pl)[32][72] = (short(*)[32][72])smem;    // [wave][q32][k64+8]
    float* scf = smem;                               // epi: [8][32][68]
    float* scd = smem + 8*32*68;                     // epi: [8][32]

    const int bid = blockIdx.x;
    const int qt = 31 - (bid >> 4);       // heavy q-tiles dispatch first (LPT)
    const int bh = bid & 15;
    const int b = bh >> 3, h = bh & 7;
    const int tid = threadIdx.x, w = tid >> 6, l = tid & 63;
    const int lr = l & 15, g = l >> 4;
    const int qend = qt*32 + 32;
    const int nkc = (qt + 2) >> 1;        // ceil(qend/64)
    const bf16x8 zf = {0,0,0,0,0,0,0,0};
    const bf16x8 ones = {16256,16256,16256,16256,16256,16256,16256,16256}; // bf16 1.0

    bf16x8 qf[2];
    #pragma unroll
    for (int nb = 0; nb < 2; ++nb)
        qf[nb] = (l < 32)
            ? *(const bf16x8*)(Qb + ((size_t)bh*TT + qt*32 + nb*16 + lr)*FF + g*8)
            : zf;

    f32x4 o[4][2] = {};       // o[mv][nb]: O^T partial over this wave's kc set
    f32x4 dacc[2] = {};       // den[q=lr] per nb (replicated across regs)

    for (int kc = w; kc < nkc; kc += 8) {
        const bool diagc = (kc == nkc - 1);           // wave-uniform
        const int act = qend - kc*64;                 // 32 or 64 on diag, else 64
        const int nmb = diagc ? (act >> 4) : 4;       // 2 or 4 (always even)
        const int kb_max = nmb >> 1;                  // 1 or 2

        // QK^T (swapped), cheap poly, diag-only mask, pack -> P
        for (int mb = 0; mb < nmb; ++mb) {
            bf16x8 kf = (l < 32)
                ? *(const bf16x8*)(Kb + ((size_t)bh*TT + kc*64 + mb*16 + lr)*FF + g*8)
                : zf;
            #pragma unroll
            for (int nb = 0; nb < 2; ++nb) {
                f32x4 z4 = {};
                f32x4 s = MFMA_BF16(kf, qf[nb], z4, 0, 0, 0);  // s pre-scaled
                float pv[4];
                if (diagc) {
                    const int qg = qt*32 + nb*16 + lr;
                    const int kg0 = kc*64 + mb*16 + g*4;
                    #pragma unroll
                    for (int r = 0; r < 4; ++r) {
                        float pp = fmaf(s[r], fmaf(s[r], 0.5f, 1.0f), 1.0f);
                        pv[r] = (kg0 + r > qg) ? 0.f : pp;
                    }
                } else {
                    #pragma unroll
                    for (int r = 0; r < 4; ++r)
                        pv[r] = fmaf(s[r], fmaf(s[r], 0.5f, 1.0f), 1.0f);
                }
                uint2 pk = { pkbf2(pv[0], pv[1]), pkbf2(pv[2], pv[3]) };
                *(uint2*)&Pl[w][nb*16 + lr][mb*16 + g*4] = pk;
            }
        }

        // PV + den:  O^T += V^T . P ;  den += ones . P
        for (int kb = 0; kb < kb_max; ++kb) {
            #pragma unroll
            for (int mv = 0; mv < 4; ++mv) {
                bf16x8 vf = *(const bf16x8*)(Vtg +
                    ((size_t)bh*64 + mv*16 + lr)*TT + kc*64 + kb*32 + g*8);
                #pragma unroll
                for (int nb = 0; nb < 2; ++nb) {
                    bf16x8 pf = *(const bf16x8*)&Pl[w][nb*16 + lr][kb*32 + g*8];
                    o[mv][nb] = MFMA_BF16(vf, pf, o[mv][nb], 0, 0, 0);
                }
            }
            #pragma unroll
            for (int nb = 0; nb < 2; ++nb) {
                bf16x8 pf = *(const bf16x8*)&Pl[w][nb*16 + lr][kb*32 + g*8];
                dacc[nb] = MFMA_BF16(ones, pf, dacc[nb], 0, 0, 0);
            }
        }
    }

    __syncthreads();   // all waves done with Pl (scratch overlays it)

    #pragma unroll
    for (int mv = 0; mv < 4; ++mv)
        #pragma unroll
        for (int nb = 0; nb < 2; ++nb)
            *(f32x4*)&scf[(size_t)(w*32 + nb*16 + lr)*68 + mv*16 + g*4] = o[mv][nb];
    if (g == 0) {      // lanes l<16: dacc[nb][0] holds den for q=lr
        scd[w*32 + lr]      = dacc[0][0];
        scd[w*32 + 16 + lr] = dacc[1][0];
    }

    __syncthreads();

    // combine 8 wave-partials, normalize, store bf16 Y (8B/thread coalesced)
    {
        const int q  = tid >> 4;           // 0..31
        const int v0 = (tid & 15) * 4;     // 0..60
        float dtot = 0.f;
        #pragma unroll
        for (int ww = 0; ww < 8; ++ww) dtot += scd[ww*32 + q];
        const float inv = 1.0f / (dtot + 1e-12f);
        float o0 = 0.f, o1 = 0.f, o2 = 0.f, o3 = 0.f;
        #pragma unroll
        for (int ww = 0; ww < 8; ++ww) {
            const float* p = &scf[(size_t)(ww*32 + q)*68 + v0];
            o0 += p[0]; o1 += p[1]; o2 += p[2]; o3 += p[3];
        }
        uint2 pk = { pkbf2(o0*inv, o1*inv), pkbf2(o2*inv, o3*inv) };
        *(uint2*)(Yb + ((size_t)(b*TT + qt*32 + q))*DD + h*HDIM + v0) = pk;
    }
}

// ---------------------------------------------------------------------------
// Kernel 3: output projection, bf16 MFMA, K-split 8-wave (round-9 structure,
// unchanged).
// ---------------------------------------------------------------------------
__global__ __launch_bounds__(512) void out_mfma(
    const ushort* __restrict__ Yb, const ushort* __restrict__ Wob,
    float* __restrict__ Out)
{
    __shared__ float sc[2][64][66];
    const int m0 = blockIdx.x * 64, n0 = blockIdx.y * 64;
    const int tid = threadIdx.x, w = tid >> 6, l = tid & 63;
    const int kw = w >> 2, mw = w & 1, nw = (w >> 1) & 1;
    const int lr = l & 15, g = l >> 4;

    f32x4 acc[2][2] = {};
    const ushort* Ar = Yb  + (size_t)(m0 + mw*32 + lr) * 512 + kw*256 + g*8;
    const ushort* Br = Wob + (size_t)(n0 + nw*32 + lr) * 512 + kw*256 + g*8;

    bf16x8 a0c = *(const bf16x8*)(Ar);
    bf16x8 a1c = *(const bf16x8*)(Ar + (size_t)16*512);
    bf16x8 b0c = *(const bf16x8*)(Br);
    bf16x8 b1c = *(const bf16x8*)(Br + (size_t)16*512);
    #pragma unroll
    for (int ks = 0; ks < 8; ++ks) {
        bf16x8 a0n = a0c, a1n = a1c, b0n = b0c, b1n = b1c;
        if (ks < 7) {
            a0n = *(const bf16x8*)(Ar + (ks+1)*32);
            a1n = *(const bf16x8*)(Ar + (size_t)16*512 + (ks+1)*32);
            b0n = *(const bf16x8*)(Br + (ks+1)*32);
            b1n = *(const bf16x8*)(Br + (size_t)16*512 + (ks+1)*32);
        }
        acc[0][0] = MFMA_BF16(a0c, b0c, acc[0][0], 0, 0, 0);
        acc[0][1] = MFMA_BF16(a0c, b1c, acc[0][1], 0, 0, 0);
        acc[1][0] = MFMA_BF16(a1c, b0c, acc[1][0], 0, 0, 0);
        acc[1][1] = MFMA_BF16(a1c, b1c, acc[1][1], 0, 0, 0);
        a0c = a0n; a1c = a1n; b0c = b0n; b1c = b1n;
    }

    #pragma unroll
    for (int mb = 0; mb < 2; ++mb)
        #pragma unroll
        for (int nb = 0; nb < 2; ++nb)
            #pragma unroll
            for (int r = 0; r < 4; ++r)
                sc[kw][mw*32 + mb*16 + g*4 + r][nw*32 + nb*16 + lr] = acc[mb][nb][r];
    __syncthreads();

    const int vl = tid & 63, rg = tid >> 6;
    #pragma unroll
    for (int j = 0; j < 8; ++j) {
        const float v = sc[0][rg*8 + j][vl] + sc[1][rg*8 + j][vl];
        Out[(size_t)(m0 + rg*8 + j)*512 + n0 + vl] = v;
    }
}

// ---------------------------------------------------------------------------
extern "C" void kernel_launch(void* const* d_in, const int* in_sizes, int n_in,
                              void* d_out, int out_size, void* d_ws, size_t ws_size,
                              hipStream_t stream) {
    const float* X  = (const float*)d_in[0];   // (2,1024,512)
    const float* Wq = (const float*)d_in[1];   // (128,512)
    const float* Wk = (const float*)d_in[2];   // (128,512)
    const float* Wv = (const float*)d_in[3];   // (512,512)
    const float* Wo = (const float*)d_in[4];   // (512,512)
    float* out = (float*)d_out;                // (2,1024,512)

    ushort* ws = (ushort*)d_ws;
    ushort* Xb  = ws;                    // 2048*512   = 1048576
    ushort* Wb  = Xb  + 1048576;         // 768*512    = 393216
    ushort* Wob = Wb  + 393216;          // 512*512    = 262144
    ushort* Qb  = Wob + 262144;          // 16*1024*16 = 262144
    ushort* Kb  = Qb  + 262144;          // 262144
    ushort* Vtg = Kb  + 262144;          // 16*64*1024 = 1048576
    ushort* Yb  = Vtg + 1048576;         // 2048*512   = 1048576

    cast_all<<<1664, 256, 0, stream>>>(X, Wq, Wk, Wv, Wo, Xb, Wb, Wob);

    dim3 g1(BT/64, 768/64);   // 32 x 12 = 384 blocks, 512 thr
    qkv_mfma<<<g1, 512, 0, stream>>>(Xb, Wb, Qb, Kb, Vtg);

    attn_mfma<<<512, 512, 0, stream>>>(Qb, Kb, Vtg, Yb);

    dim3 g3(BT/64, DD/64);    // 32 x 8 = 256 blocks, 512 thr
    out_mfma<<<g3, 512, 0, stream>>>(Yb, Wob, out);
}